// Round 1
// baseline (178.559 us; speedup 1.0000x reference)
//
#include <hip/hip_runtime.h>
#include <cmath>

#define BN 16
#define CDIM 64
#define TOT 8192
#define KNB 20
#define CN 512
#define NSTEPS 8
#define WPB 8            // walkers per block (4 waves x 2 walkers/wave, 32 lanes each)
#define BPB 64           // blocks per batch (CN / WPB)
#define NNB 10           // neighbors handled per 16-lane half-group (2 groups/walker)
#define WSTRIDE 577      // per-walker LDS out-buffer stride (64*9 + 1 pad)
#define POISON 0xAAAAAAAAu  // harness ws poison; sign-bit 1 -> never a softmax value

typedef float vf4 __attribute__((ext_vector_type(4)));

// shared contraction so pa (precompute) == walker's exact FMA tree
__device__ __forceinline__ float dot4(float a, float b, float c, float d,
                                      float wa, float wb, float wc, float wd) {
  return a * wa + b * wb + c * wc + d * wd;
}

template <int CTRL>
__device__ __forceinline__ float dpp_add(float v) {
  int o = __builtin_amdgcn_update_dpp(0, __float_as_int(v), CTRL, 0xF, 0xF, true);
  return v + __int_as_float(o);
}

// butterfly sum across a 16-lane group — pure VALU; balanced binary tree
__device__ __forceinline__ float gred16(float v) {
  v = dpp_add<0xB1>(v);   // quad_perm xor1
  v = dpp_add<0x4E>(v);   // quad_perm xor2
  v = dpp_add<0x141>(v);  // row_half_mirror (xor4)
  v = dpp_add<0x140>(v);  // row_mirror (xor8)
  return v;
}

// ===================== K1: transpose + pa (plain cached stores) =====================
// Stream-order K1->K2 replaces the old in-kernel sc1+flag protocol: end-of-kernel
// agent release flushes L2 to MALL, K2's dispatch acquire invalidates stale lines.
// pa butterfly bracketing == old ((sA+sB)+(sC+sD)) tree -> bitwise-identical pa.
__global__ __launch_bounds__(256) void prep_kernel(
    const float* __restrict__ x, const float* __restrict__ agent_w,
    float* __restrict__ xt, float* __restrict__ pa) {
  __shared__ float tile[64][65];
  const int tid = threadIdx.x;
  const int bI  = blockIdx.x;
  const int b   = (bI & 7) | (((bI >> 10) & 1) << 3);  // XCD-pinned like the walk
  const int t0  = ((bI >> 3) & 127) << 6;              // 128 tiles of 64 nodes per batch
  const vf4 aw  = *(const vf4*)(agent_w + ((tid & 15) << 2));
#pragma unroll
  for (int k = 0; k < 4; ++k) {
    int fid = tid + (k << 8);
    int cc = fid >> 4, qt = (fid & 15) << 2;
    float4 vv = *(const float4*)(x + ((size_t)b * CDIM + cc) * TOT + t0 + qt);
    tile[cc][qt + 0] = vv.x; tile[cc][qt + 1] = vv.y;
    tile[cc][qt + 2] = vv.z; tile[cc][qt + 3] = vv.w;
  }
  __syncthreads();
#pragma unroll
  for (int k = 0; k < 4; ++k) {
    int fid = tid + (k << 8);
    int tt = fid >> 4, qc = (fid & 15) << 2;
    vf4 vv = {tile[qc + 0][tt], tile[qc + 1][tt], tile[qc + 2][tt], tile[qc + 3][tt]};
    *(vf4*)(xt + ((size_t)b * TOT + t0 + tt) * CDIM + qc) = vv;
    // fused pa: lane L holds q[L]; butterfly == old balanced tree, bitwise-same
    float part = gred16(dot4(vv.x, vv.y, vv.z, vv.w, aw.x, aw.y, aw.z, aw.w));
    if ((tid & 15) == 0) pa[(size_t)b * TOT + t0 + tt] = part;
  }
}

// ===================== K2: the walk (32-lane walkers, data-is-flag sync) ============
__global__ __launch_bounds__(256, 4) void walk_kernel(
    const int* __restrict__ adj, const int* __restrict__ cur,
    const float* __restrict__ agent_w, const float* __restrict__ agent_gamma,
    const float* __restrict__ agent_beta, const float* __restrict__ agent_mean,
    const float* __restrict__ agent_var, const float* __restrict__ mom_w,
    const float* __restrict__ mom_gamma, const float* __restrict__ mom_beta,
    const float* __restrict__ mom_mean, const float* __restrict__ mom_var,
    const float* __restrict__ xt, const float* __restrict__ pa,
    float* __restrict__ out, float* __restrict__ sbuf) {
  __shared__ float lds_out[WPB * WSTRIDE];  // 8*577*4 = 18464 B
  const int tid  = threadIdx.x;
  const int lane = tid & 63;
  const int wv   = tid >> 6;
  const int half = lane >> 5;          // walker within wave (2 walkers/wave)
  const int g2   = (lane >> 4) & 1;    // half-group A(0): j 0..9, B(1): j 10..19
  const int L    = lane & 15;
  const int w    = wv * 2 + half;      // walker in block, 0..7
  const int b     = (blockIdx.x & 7) | (((blockIdx.x >> 9) & 1) << 3);
  const int chunk = (blockIdx.x >> 3) & 63;
  const int n     = chunk * WPB + w;
  const int c0    = L << 2;
  // consumer word offsets for the momentum-coeff scramble (data-is-flag):
  // word[2m]=S0[m], word[2m+1]=S1[m]; A0=word[(4n&1023)+off], A1=+2  (off = n>=256)
  const int mbase = (n << 2) & 1023;
  const int moff  = (n >= 256) ? 1 : 0;

  const vf4 aw2  = *(const vf4*)(agent_w + 64 + c0);
  const vf4 mw0a = *(const vf4*)(mom_w + c0);
  const vf4 mw0b = *(const vf4*)(mom_w + 64 + c0);
  const vf4 mw1a = *(const vf4*)(mom_w + 128 + c0);
  const vf4 mw1b = *(const vf4*)(mom_w + 192 + c0);
  const float amean  = agent_mean[0];
  const float abeta  = agent_beta[0];
  const float ainv   = agent_gamma[0] / sqrtf(agent_var[0] + 1e-5f);
  const float m0mean = mom_mean[0], m1mean = mom_mean[1];
  const float m0inv  = mom_gamma[0] / sqrtf(mom_var[0] + 1e-5f);
  const float m1inv  = mom_gamma[1] / sqrtf(mom_var[1] + 1e-5f);
  const float m0beta = mom_beta[0], m1beta = mom_beta[1];

  const float* xb   = xt + (size_t)b * TOT * CDIM;
  const float* pab  = pa + (size_t)b * TOT;
  const int*   adjb = adj + (size_t)b * TOT * KNB;
  float*       lout = lds_out + w * WSTRIDE;

  int t = cur[b * CN + n];
  vf4 pf = *(const vf4*)(xb + (size_t)t * CDIM + c0);
  vf4 cf = pf;
  vf4 u  = (vf4){0.f, 0.f, 0.f, 0.f};
  float A0v = 0.f, A1v = 0.f;

  int   idx[NNB];
  vf4   nv[NNB];
  float pav[NNB];
  float sq[NNB];
  {
    // per-group neighbor slice; byte offset t*80 + g2*40 is 8B-aligned -> int2 x5
    const int2* ar = (const int2*)(adjb + (size_t)t * KNB + g2 * NNB);
    int2 a0 = ar[0], a1 = ar[1], a2 = ar[2], a3 = ar[3], a4 = ar[4];
    idx[0] = a0.x; idx[1] = a0.y; idx[2] = a1.x; idx[3] = a1.y; idx[4] = a2.x;
    idx[5] = a2.y; idx[6] = a3.x; idx[7] = a3.y; idx[8] = a4.x; idx[9] = a4.y;
#pragma unroll
    for (int j = 0; j < NNB; ++j) {
      nv[j]  = *(const vf4*)(xb + (size_t)idx[j] * CDIM + c0);
      pav[j] = pab[idx[j]];
    }
  }

#pragma unroll 1
  for (int s = 0; s < NSTEPS; ++s) {
    float n1 = 0.f;
    if (s > 0) {
      // A0v/A1v came from the data-poll at the bottom of step s-1
      pf.x = A0v * cf.x + A1v * pf.x;
      pf.y = A0v * cf.y + A1v * pf.y;
      pf.z = A0v * cf.z + A1v * pf.z;
      pf.w = A0v * cf.w + A1v * pf.w;
      u.x = cf.x - pf.x; u.y = cf.y - pf.y; u.z = cf.z - pf.z; u.w = cf.w - pf.w;
      n1 = sqrtf(gred16(u.x * u.x + u.y * u.y + u.z * u.z + u.w * u.w));
    }
    float pw = gred16(pf.x * aw2.x + pf.y * aw2.y + pf.z * aw2.z + pf.w * aw2.w);

    float bestp = -3.4e38f;
    int   bestt = 0;
    vf4   bestv = (vf4){0.f, 0.f, 0.f, 0.f};
#pragma unroll
    for (int j = 0; j < NNB; ++j) {
      const vf4 v = nv[j];
      float logit = (pav[j] + pw - amean) * ainv + abeta;
      float p;
      if (s > 0) {
        float tx = v.x - cf.x, ty = v.y - cf.y, tz = v.z - cf.z, tw = v.w - cf.w;
        float su = tx * u.x + ty * u.y + tz * u.z + tw * u.w;
        su = gred16(su);
        float den  = fmaxf(n1 * sq[j], 1e-8f);    // sq[j]=sqrtf(gred16(sn)) precomputed
        float cosv = su * __builtin_amdgcn_rcpf(den);
        float dfac = fminf(fmaxf(1.0f + cosv, 0.0f), 1.0f);
        p = logit * dfac;
      } else {
        p = logit;
      }
      if (p > bestp) { bestp = p; bestt = idx[j]; bestv = v; }
    }
    // merge the two half-groups of this walker (lanes l <-> l^16 within the 32-lane
    // walker). Tie -> group A (lower j): exact first-max semantics over j=0..19.
    {
      float op = __shfl_xor(bestp, 16, 32);
      int   ot = __shfl_xor(bestt, 16, 32);
      float ox = __shfl_xor(bestv.x, 16, 32);
      float oy = __shfl_xor(bestv.y, 16, 32);
      float oz = __shfl_xor(bestv.z, 16, 32);
      float ow = __shfl_xor(bestv.w, 16, 32);
      bool take = g2 ? !(bestp > op) : (op > bestp);
      if (take) { bestt = ot; bestv.x = ox; bestv.y = oy; bestv.z = oz; bestv.w = ow; }
    }
    cf = bestv;
    t  = bestt;
    if (g2 == 0) {
      lout[(c0 + 0) * 9 + s] = cf.x;
      lout[(c0 + 1) * 9 + s] = cf.y;
      lout[(c0 + 2) * 9 + s] = cf.z;
      lout[(c0 + 3) * 9 + s] = cf.w;
    }

    if (s < NSTEPS - 1) {
      // ---- momentum logits for step s+1; publish (S0,S1) as ONE packed 8-B
      //      relaxed store. Data IS the flag (poison-sentinel) -> NO drain. ----
      float p0 = cf.x * mw0a.x + cf.y * mw0a.y + cf.z * mw0a.z + cf.w * mw0a.w +
                 pf.x * mw0b.x + pf.y * mw0b.y + pf.z * mw0b.z + pf.w * mw0b.w;
      float p1 = cf.x * mw1a.x + cf.y * mw1a.y + cf.z * mw1a.z + cf.w * mw1a.w +
                 pf.x * mw1b.x + pf.y * mw1b.y + pf.z * mw1b.z + pf.w * mw1b.w;
      p0 = gred16(p0);
      p1 = gred16(p1);
      float mlog0 = (p0 - m0mean) * m0inv + m0beta;
      float mlog1 = (p1 - m1mean) * m1inv + m1beta;
      float mx = fmaxf(mlog0, mlog1);
      float e0 = expf(mlog0 - mx), e1 = expf(mlog1 - mx);
      float sinv = 1.0f / (e0 + e1);
      float* sb = sbuf + ((size_t)(b * NSTEPS + s + 1) << 10);
      if (L == 0 && g2 == 0) {
        unsigned long long pk =
            (unsigned long long)__float_as_uint(e0 * sinv) |
            ((unsigned long long)__float_as_uint(e1 * sinv) << 32);
        __hip_atomic_store((unsigned long long*)sb + n, pk,
                           __ATOMIC_RELAXED, __HIP_MEMORY_SCOPE_AGENT);
      }
      // ---- prefetch next neighborhood BEFORE the poll (t-dependent only) ----
      const int2* ar = (const int2*)(adjb + (size_t)t * KNB + g2 * NNB);
      int2 a0 = ar[0], a1 = ar[1], a2 = ar[2], a3 = ar[3], a4 = ar[4];
      idx[0] = a0.x; idx[1] = a0.y; idx[2] = a1.x; idx[3] = a1.y; idx[4] = a2.x;
      idx[5] = a2.y; idx[6] = a3.x; idx[7] = a3.y; idx[8] = a4.x; idx[9] = a4.y;
#pragma unroll
      for (int j = 0; j < NNB; ++j) {
        nv[j]  = *(const vf4*)(xb + (size_t)idx[j] * CDIM + c0);
        pav[j] = pab[idx[j]];
      }
      // ---- pf-independent cosine prefix in the poll shadow (bitwise-same) ----
#pragma unroll
      for (int j = 0; j < NNB; ++j) {
        const vf4 v = nv[j];
        float tx = v.x - cf.x, ty = v.y - cf.y, tz = v.z - cf.z, tw = v.w - cf.w;
        float sn = tx * tx + ty * ty + tz * tz + tw * tw;
        sq[j] = sqrtf(gred16(sn));
      }
      // ---- poll the producer S words directly (one MALL round trip) ----
      {
        const unsigned* sbw = (const unsigned*)sb;
        const unsigned* q0p = sbw + mbase + moff;
        const unsigned* q2p = q0p + 2;
        unsigned w0, w2;
        for (;;) {
          w0 = __hip_atomic_load(q0p, __ATOMIC_RELAXED, __HIP_MEMORY_SCOPE_AGENT);
          w2 = __hip_atomic_load(q2p, __ATOMIC_RELAXED, __HIP_MEMORY_SCOPE_AGENT);
          if (w0 != POISON && w2 != POISON) break;
          __builtin_amdgcn_s_sleep(1);
        }
        A0v = __uint_as_float(w0);
        A1v = __uint_as_float(w2);
      }
      asm volatile("" ::: "memory");
    }
  }

  // single coalesced write phase: out[b][c][n][0..7] = 32B per (c,n)
  // group A writes channel rows c0+0..1, group B writes c0+2..3 (written by A's
  // lanes into LDS; same-wave ds ordering makes them visible without a barrier)
#pragma unroll
  for (int e = 0; e < 2; ++e) {
    const int ee = (g2 << 1) + e;
    const float* src = lout + (c0 + ee) * 9;
    float4 w0 = make_float4(src[0], src[1], src[2], src[3]);
    float4 w1 = make_float4(src[4], src[5], src[6], src[7]);
    float* op = out + (((size_t)(b * CDIM + c0 + ee) * CN) + n) * NSTEPS;
    *(float4*)(op)     = w0;
    *(float4*)(op + 4) = w1;
  }
}

extern "C" void kernel_launch(void* const* d_in, const int* in_sizes, int n_in,
                              void* d_out, int out_size, void* d_ws, size_t ws_size,
                              hipStream_t stream) {
  (void)in_sizes; (void)n_in; (void)out_size; (void)ws_size;
  const float* x          = (const float*)d_in[1];
  const int*   adj        = (const int*)d_in[2];
  const int*   cur        = (const int*)d_in[3];
  const float* agent_w    = (const float*)d_in[4];
  const float* agent_gamma= (const float*)d_in[5];
  const float* agent_beta = (const float*)d_in[6];
  const float* agent_mean = (const float*)d_in[7];
  const float* agent_var  = (const float*)d_in[8];
  const float* mom_w      = (const float*)d_in[9];
  const float* mom_gamma  = (const float*)d_in[10];
  const float* mom_beta   = (const float*)d_in[11];
  const float* mom_mean   = (const float*)d_in[12];
  const float* mom_var    = (const float*)d_in[13];
  float* out = (float*)d_out;

  char* ws = (char*)d_ws;
  const size_t xt_bytes   = (size_t)BN * TOT * CDIM * sizeof(float);       // 33.5 MB
  const size_t sbuf_bytes = (size_t)BN * NSTEPS * 2 * CN * sizeof(float);  // 512 KB
  float* xt   = (float*)ws;
  float* sbuf = (float*)(ws + xt_bytes);   // per-step S pairs; poison = sentinel
  float* pab  = (float*)(ws + xt_bytes + sbuf_bytes);

  prep_kernel<<<2048, 256, 0, stream>>>(x, agent_w, xt, pab);
  walk_kernel<<<BN * BPB, 256, 0, stream>>>(adj, cur, agent_w, agent_gamma, agent_beta,
                                            agent_mean, agent_var, mom_w, mom_gamma,
                                            mom_beta, mom_mean, mom_var,
                                            xt, pab, out, sbuf);
}

// Round 2
// 160.786 us; speedup vs baseline: 1.1105x; 1.1105x over previous
//
#include <hip/hip_runtime.h>
#include <cmath>

#define BN 16
#define CDIM 64
#define TOT 8192
#define KNB 20
#define CN 512
#define NSTEPS 8
#define WPB 16           // walkers per block (4 waves x 4 groups of 16 lanes)
#define BPB 32           // blocks per batch (CN / WPB)
#define WSTRIDE 577      // per-walker LDS out-buffer stride (64*9 + 1 pad)
#define LINE 32          // uints per flag line (128B, no false sharing)
#define MAGIC 0x5A17ECE1u   // phase-1 write-once slots (!= poison)
#define POISON 0xAAAAAAAAu  // harness ws poison; sign-bit 1 -> never a softmax value

typedef float vf4 __attribute__((ext_vector_type(4)));
typedef unsigned uv4 __attribute__((ext_vector_type(4)));

// shared contraction so pa (precompute) == walker's exact FMA tree
__device__ __forceinline__ float dot4(float a, float b, float c, float d,
                                      float wa, float wb, float wc, float wd) {
  return a * wa + b * wb + c * wc + d * wd;
}

template <int CTRL>
__device__ __forceinline__ float dpp_add(float v) {
  int o = __builtin_amdgcn_update_dpp(0, __float_as_int(v), CTRL, 0xF, 0xF, true);
  return v + __int_as_float(o);
}

// butterfly sum across the 16-lane group — pure VALU; balanced binary tree
// (bitwise == ((q0+q1)+(q2+q3)) + ... pairwise tree; addition commutes exactly)
__device__ __forceinline__ float gred16(float v) {
  v = dpp_add<0xB1>(v);   // quad_perm xor1
  v = dpp_add<0x4E>(v);   // quad_perm xor2
  v = dpp_add<0x141>(v);  // row_half_mirror (xor4)
  v = dpp_add<0x140>(v);  // row_mirror (xor8)
  return v;
}

// 32-bit byte-offset gather helpers: base is wave-uniform (SGPR pair), offset is a
// 32-bit VGPR -> compiler emits global_load saddr (1 VALU addr op vs 64-bit mul/add)
__device__ __forceinline__ const vf4* vptr(const float* base, unsigned boff) {
  return (const vf4*)((const char*)base + boff);
}
__device__ __forceinline__ float ldf(const float* base, unsigned boff) {
  return *(const float*)((const char*)base + boff);
}

__global__ __launch_bounds__(256, 2) void walk_kernel(
    const float* __restrict__ x, const int* __restrict__ adj, const int* __restrict__ cur,
    const float* __restrict__ agent_w, const float* __restrict__ agent_gamma,
    const float* __restrict__ agent_beta, const float* __restrict__ agent_mean,
    const float* __restrict__ agent_var, const float* __restrict__ mom_w,
    const float* __restrict__ mom_gamma, const float* __restrict__ mom_beta,
    const float* __restrict__ mom_mean, const float* __restrict__ mom_var,
    float* __restrict__ xt, float* __restrict__ pa,
    float* __restrict__ out, float* __restrict__ sbuf,
    unsigned int* __restrict__ pflag) {
  __shared__ float lds_out[WPB * WSTRIDE];  // walk-phase out buffer; aliased as tile below
  const int tid  = threadIdx.x;
  const int lane = tid & 63;
  const int wv   = tid >> 6;
  const int g    = lane >> 4;
  const int L    = lane & 15;
  const int b     = (blockIdx.x & 7) + (((blockIdx.x >> 8) & 1) << 3);
  const int chunk = (blockIdx.x >> 3) & 31;
  const int w     = wv * 4 + g;
  const int n     = chunk * WPB + w;
  const int c0    = L << 2;
  // consumer word offsets for the momentum-coeff scramble (data-is-flag):
  // word[2m]=S0[m], word[2m+1]=S1[m]; A0=word[(4n&1023)+off], A1=+2  (off = n>=256)
  const int mbase = (n << 2) & 1023;
  const int moff  = (chunk >= 16) ? 1 : 0;   // == (n >= 256), block-uniform

  // ================= phase 1: transpose + pa (fused, sc1 -> MALL) =================
  {
    float (*tile)[65] = (float (*)[65])lds_out;  // 64*65*4 = 16.6 KB, aliased
    const vf4 awp = *(const vf4*)(agent_w + (L << 2));
#pragma unroll 1
    for (int i = 0; i < 4; ++i) {
      const int t0 = ((chunk << 2) + i) << 6;
#pragma unroll
      for (int k = 0; k < 4; ++k) {
        int fid = tid + k * 256;
        int cc = fid >> 4, qt = (fid & 15) << 2;
        float4 vv = *(const float4*)(x + ((size_t)b * CDIM + cc) * TOT + t0 + qt);
        tile[cc][qt + 0] = vv.x; tile[cc][qt + 1] = vv.y;
        tile[cc][qt + 2] = vv.z; tile[cc][qt + 3] = vv.w;
      }
      __syncthreads();
#pragma unroll
      for (int k = 0; k < 4; ++k) {
        int fid = tid + k * 256;
        int tt = fid >> 4, qc = (fid & 15) << 2;
        vf4 vv = {tile[qc + 0][tt], tile[qc + 1][tt], tile[qc + 2][tt], tile[qc + 3][tt]};
        float* dst = xt + ((size_t)b * TOT + t0 + tt) * CDIM + qc;
        asm volatile("global_store_dwordx4 %0, %1, off sc0 sc1" :: "v"(dst), "v"(vv) : "memory");
        // fused pa: 16 lanes of this row hold channels qc..qc+3 of node tt;
        // gred16 == round-0's ((sA+sB)+(sC+sD)) balanced tree, bitwise-identical
        float part = gred16(dot4(vv.x, vv.y, vv.z, vv.w, awp.x, awp.y, awp.z, awp.w));
        if ((tid & 15) == 0)
          __hip_atomic_store(pa + (size_t)b * TOT + t0 + tt, part,
                             __ATOMIC_RELAXED, __HIP_MEMORY_SCOPE_AGENT);
      }
      __syncthreads();
    }
    asm volatile("s_waitcnt vmcnt(0)" ::: "memory");  // all sc1 stores at MALL
    __builtin_amdgcn_s_barrier();
    if (tid == 0)
      __hip_atomic_store(pflag + ((size_t)b * BPB + chunk) * LINE, MAGIC,
                         __ATOMIC_RELAXED, __HIP_MEMORY_SCOPE_AGENT);
    if (tid < BPB) {  // wait for all 32 blocks of this batch
      const unsigned int* f = pflag + ((size_t)b * BPB + tid) * LINE;
      while (__hip_atomic_load(f, __ATOMIC_RELAXED, __HIP_MEMORY_SCOPE_AGENT) != MAGIC)
        __builtin_amdgcn_s_sleep(2);
    }
    __builtin_amdgcn_s_barrier();
    asm volatile("" ::: "memory");
  }

  // ================= phase 2: the walk (data-is-flag sync) =================
  const vf4 aw2  = *(const vf4*)(agent_w + 64 + c0);
  const vf4 mw0a = *(const vf4*)(mom_w + c0);
  const vf4 mw0b = *(const vf4*)(mom_w + 64 + c0);
  const vf4 mw1a = *(const vf4*)(mom_w + 128 + c0);
  const vf4 mw1b = *(const vf4*)(mom_w + 192 + c0);
  const float amean  = agent_mean[0];
  const float abeta  = agent_beta[0];
  const float ainv   = agent_gamma[0] / sqrtf(agent_var[0] + 1e-5f);
  const float m0mean = mom_mean[0], m1mean = mom_mean[1];
  const float m0inv  = mom_gamma[0] / sqrtf(mom_var[0] + 1e-5f);
  const float m1inv  = mom_gamma[1] / sqrtf(mom_var[1] + 1e-5f);
  const float m0beta = mom_beta[0], m1beta = mom_beta[1];

  const float* xb   = xt + (size_t)b * TOT * CDIM;
  const float* pab  = pa + (size_t)b * TOT;
  const int*   adjb = adj + (size_t)b * TOT * KNB;
  float*       lout = lds_out + w * WSTRIDE;

  int t = cur[b * CN + n];
  vf4 pf = *vptr(xb, ((unsigned)t << 8) + (unsigned)(c0 << 2));
  vf4 cf = pf;
  vf4 u  = (vf4){0.f, 0.f, 0.f, 0.f};
  float A0v = 0.f, A1v = 0.f;

  int   idx[KNB];
  vf4   nv[KNB];
  float pav[KNB];   // holds pav[j] * ainv (hoisted BN scale)
  float sq[KNB];
  {
    const int4* arow = (const int4*)((const char*)adjb + (unsigned)t * 80u);
    int4 q0 = arow[0], q1 = arow[1], q2 = arow[2], q3 = arow[3], q4 = arow[4];
    int tmp[KNB] = {q0.x, q0.y, q0.z, q0.w, q1.x, q1.y, q1.z, q1.w,
                    q2.x, q2.y, q2.z, q2.w, q3.x, q3.y, q3.z, q3.w,
                    q4.x, q4.y, q4.z, q4.w};
#pragma unroll
    for (int j = 0; j < KNB; ++j) idx[j] = tmp[j];
#pragma unroll
    for (int j = 0; j < KNB; ++j) {
      nv[j]  = *vptr(xb, ((unsigned)idx[j] << 8) + (unsigned)(c0 << 2));
      pav[j] = ldf(pab, (unsigned)idx[j] << 2) * ainv;
    }
  }

  __builtin_amdgcn_s_setprio(1);   // walker chain is the global critical path
#pragma unroll 1
  for (int s = 0; s < NSTEPS; ++s) {
    float n1 = 0.f;
    if (s > 0) {
      // A0v/A1v came from the data-poll at the bottom of step s-1
      pf.x = A0v * cf.x + A1v * pf.x;
      pf.y = A0v * cf.y + A1v * pf.y;
      pf.z = A0v * cf.z + A1v * pf.z;
      pf.w = A0v * cf.w + A1v * pf.w;
      u.x = cf.x - pf.x; u.y = cf.y - pf.y; u.z = cf.z - pf.z; u.w = cf.w - pf.w;
      n1 = sqrtf(gred16(u.x * u.x + u.y * u.y + u.z * u.z + u.w * u.w));
    }
    float pw = gred16(pf.x * aw2.x + pf.y * aw2.y + pf.z * aw2.z + pf.w * aw2.w);
    // logit = pav[j]*ainv + lbase  ==  (pav[j]+pw-amean)*ainv + abeta  (~1e-7 reorder)
    float lbase = (pw - amean) * ainv + abeta;

    float bestp = -3.4e38f;
    int   bestt = 0;
    vf4   bestv = (vf4){0.f, 0.f, 0.f, 0.f};
#pragma unroll
    for (int j = 0; j < KNB; ++j) {
      const vf4 v = nv[j];
      float logit = pav[j] + lbase;
      float p;
      if (s > 0) {
        float tx = v.x - cf.x, ty = v.y - cf.y, tz = v.z - cf.z, tw = v.w - cf.w;
        float su = tx * u.x + ty * u.y + tz * u.z + tw * u.w;
        su = gred16(su);
        float den  = fmaxf(n1 * sq[j], 1e-8f);    // sq[j]=sqrtf(gred16(sn)) precomputed
        float cosv = su * __builtin_amdgcn_rcpf(den);
        float dfac = fminf(fmaxf(1.0f + cosv, 0.0f), 1.0f);
        p = logit * dfac;
      } else {
        p = logit;
      }
      if (p > bestp) { bestp = p; bestt = idx[j]; bestv = v; }
    }
    cf = bestv;
    t  = bestt;
    lout[(c0 + 0) * 9 + s] = cf.x;
    lout[(c0 + 1) * 9 + s] = cf.y;
    lout[(c0 + 2) * 9 + s] = cf.z;
    lout[(c0 + 3) * 9 + s] = cf.w;

    if (s < NSTEPS - 1) {
      // ---- momentum logits for step s+1; publish (S0,S1) as ONE packed 8-B
      //      relaxed store. Data IS the flag (poison-sentinel) -> NO drain. ----
      float p0 = cf.x * mw0a.x + cf.y * mw0a.y + cf.z * mw0a.z + cf.w * mw0a.w +
                 pf.x * mw0b.x + pf.y * mw0b.y + pf.z * mw0b.z + pf.w * mw0b.w;
      float p1 = cf.x * mw1a.x + cf.y * mw1a.y + cf.z * mw1a.z + cf.w * mw1a.w +
                 pf.x * mw1b.x + pf.y * mw1b.y + pf.z * mw1b.z + pf.w * mw1b.w;
      p0 = gred16(p0);
      p1 = gred16(p1);
      float mlog0 = (p0 - m0mean) * m0inv + m0beta;
      float mlog1 = (p1 - m1mean) * m1inv + m1beta;
      float mx = fmaxf(mlog0, mlog1);
      float e0 = expf(mlog0 - mx), e1 = expf(mlog1 - mx);
      float sinv = 1.0f / (e0 + e1);
      float* sb = sbuf + ((size_t)(b * NSTEPS + s + 1) << 10);
      if (L == 0) {
        unsigned long long pk =
            (unsigned long long)__float_as_uint(e0 * sinv) |
            ((unsigned long long)__float_as_uint(e1 * sinv) << 32);
        __hip_atomic_store((unsigned long long*)sb + n, pk,
                           __ATOMIC_RELAXED, __HIP_MEMORY_SCOPE_AGENT);
      }
      __builtin_amdgcn_s_setprio(0);   // shadow work below is hideable
      // ---- early probe: one 16B MALL read covering BOTH producer packets;
      //      issued now so the round trip hides under prefetch + sq shadow ----
      const char* pollp = (const char*)sb + ((unsigned)mbase << 2);
      uv4 pr;
      asm volatile("global_load_dwordx4 %0, %1, off sc0 sc1"
                   : "=v"(pr) : "v"(pollp) : "memory");
      // ---- prefetch next neighborhood BEFORE the poll (t-dependent only) ----
      const int4* arow = (const int4*)((const char*)adjb + (unsigned)t * 80u);
      int4 q0 = arow[0], q1 = arow[1], q2 = arow[2], q3 = arow[3], q4 = arow[4];
      int tmp[KNB] = {q0.x, q0.y, q0.z, q0.w, q1.x, q1.y, q1.z, q1.w,
                      q2.x, q2.y, q2.z, q2.w, q3.x, q3.y, q3.z, q3.w,
                      q4.x, q4.y, q4.z, q4.w};
#pragma unroll
      for (int j = 0; j < KNB; ++j) idx[j] = tmp[j];
#pragma unroll
      for (int j = 0; j < KNB; ++j) {
        nv[j]  = *vptr(xb, ((unsigned)idx[j] << 8) + (unsigned)(c0 << 2));
        pav[j] = ldf(pab, (unsigned)idx[j] << 2) * ainv;
      }
      // ---- pf-independent cosine prefix in the poll shadow (bitwise-same) ----
#pragma unroll
      for (int j = 0; j < KNB; ++j) {
        const vf4 v = nv[j];
        float tx = v.x - cf.x, ty = v.y - cf.y, tz = v.z - cf.z, tw = v.w - cf.w;
        float sn = tx * tx + ty * ty + tz * tz + tw * tw;
        sq[j] = sqrtf(gred16(sn));
      }
      // ---- consume probe; fall into poll loop only if producers were late ----
      {
        asm volatile("s_waitcnt vmcnt(0)" ::: "memory");
        unsigned w0 = moff ? pr.y : pr.x;
        unsigned w2 = moff ? pr.w : pr.z;
        while (w0 == POISON || w2 == POISON) {
          __builtin_amdgcn_s_sleep(1);
          asm volatile("global_load_dwordx4 %0, %1, off sc0 sc1"
                       : "=v"(pr) : "v"(pollp) : "memory");
          asm volatile("s_waitcnt vmcnt(0)" ::: "memory");
          w0 = moff ? pr.y : pr.x;
          w2 = moff ? pr.w : pr.z;
        }
        A0v = __uint_as_float(w0);
        A1v = __uint_as_float(w2);
      }
      __builtin_amdgcn_s_setprio(1);   // back on the critical chain
      asm volatile("" ::: "memory");
    }
  }

  // single coalesced write phase: out[b][c][n][0..7] = 32B per (c,n)
#pragma unroll
  for (int e = 0; e < 4; ++e) {
    const float* src = lout + (c0 + e) * 9;
    float4 w0 = make_float4(src[0], src[1], src[2], src[3]);
    float4 w1 = make_float4(src[4], src[5], src[6], src[7]);
    float* op = out + (((size_t)(b * CDIM + c0 + e) * CN) + n) * NSTEPS;
    *(float4*)(op)     = w0;
    *(float4*)(op + 4) = w1;
  }
}

extern "C" void kernel_launch(void* const* d_in, const int* in_sizes, int n_in,
                              void* d_out, int out_size, void* d_ws, size_t ws_size,
                              hipStream_t stream) {
  (void)in_sizes; (void)n_in; (void)out_size; (void)ws_size;
  const float* x          = (const float*)d_in[1];
  const int*   adj        = (const int*)d_in[2];
  const int*   cur        = (const int*)d_in[3];
  const float* agent_w    = (const float*)d_in[4];
  const float* agent_gamma= (const float*)d_in[5];
  const float* agent_beta = (const float*)d_in[6];
  const float* agent_mean = (const float*)d_in[7];
  const float* agent_var  = (const float*)d_in[8];
  const float* mom_w      = (const float*)d_in[9];
  const float* mom_gamma  = (const float*)d_in[10];
  const float* mom_beta   = (const float*)d_in[11];
  const float* mom_mean   = (const float*)d_in[12];
  const float* mom_var    = (const float*)d_in[13];
  float* out = (float*)d_out;

  char* ws = (char*)d_ws;
  const size_t xt_bytes   = (size_t)BN * TOT * CDIM * sizeof(float);       // 33.5 MB
  const size_t sbuf_bytes = (size_t)BN * NSTEPS * 2 * CN * sizeof(float);  // 512 KB
  const size_t pa_bytes   = (size_t)BN * TOT * sizeof(float);              // 512 KB
  float*        xt    = (float*)ws;
  float*        sbuf  = (float*)(ws + xt_bytes);   // per-step S pairs; poison = sentinel
  float*        pab   = (float*)(ws + xt_bytes + sbuf_bytes);
  unsigned int* pflag = (unsigned int*)(ws + xt_bytes + sbuf_bytes + pa_bytes);

  walk_kernel<<<BN * BPB, 256, 0, stream>>>(x, adj, cur, agent_w, agent_gamma, agent_beta,
                                            agent_mean, agent_var, mom_w, mom_gamma, mom_beta,
                                            mom_mean, mom_var, xt, pab, out, sbuf, pflag);
}

// Round 5
// 153.634 us; speedup vs baseline: 1.1622x; 1.0466x over previous
//
#include <hip/hip_runtime.h>
#include <cmath>

#define BN 16
#define CDIM 64
#define TOT 8192
#define KNB 20
#define CN 512
#define NSTEPS 8
#define WPB 16           // walkers per block (4 waves x 4 groups of 16 lanes)
#define BPB 32           // blocks per batch (CN / WPB)
#define WSTRIDE 577      // per-walker LDS out-buffer stride (64*9 + 1 pad)
#define LINE 32          // uints per flag line (128B, no false sharing)
#define MAGIC 0x5A17ECE1u   // phase-1 write-once slots (!= poison)
#define POISON 0xAAAAAAAAu  // harness ws poison; sign-bit 1 -> never a softmax value

typedef float vf4 __attribute__((ext_vector_type(4)));

// shared contraction so pa (precompute) == walker's exact FMA tree
__device__ __forceinline__ float dot4(float a, float b, float c, float d,
                                      float wa, float wb, float wc, float wd) {
  return a * wa + b * wb + c * wc + d * wd;
}

template <int CTRL>
__device__ __forceinline__ float dpp_add(float v) {
  int o = __builtin_amdgcn_update_dpp(0, __float_as_int(v), CTRL, 0xF, 0xF, true);
  return v + __int_as_float(o);
}
template <int CTRL>
__device__ __forceinline__ float dppf(float v) {
  return __int_as_float(__builtin_amdgcn_update_dpp(0, __float_as_int(v), CTRL, 0xF, 0xF, true));
}
template <int CTRL>
__device__ __forceinline__ int dppi(int v) {
  return __builtin_amdgcn_update_dpp(0, v, CTRL, 0xF, 0xF, true);
}
// true xor4/xor8 lane exchange via ds_swizzle BitMode: offset=(xor<<10)|0x1F.
// Stays within 32-lane halves; our 16-lane groups never straddle one.
template <int MASK>
__device__ __forceinline__ float swzf(float v) {
  return __int_as_float(__builtin_amdgcn_ds_swizzle(__float_as_int(v), MASK));
}
template <int MASK>
__device__ __forceinline__ int swzi(int v) {
  return __builtin_amdgcn_ds_swizzle(v, MASK);
}

// butterfly sum across the 16-lane group — pure VALU; balanced binary tree
__device__ __forceinline__ float gred16(float v) {
  v = dpp_add<0xB1>(v);   // quad_perm xor1
  v = dpp_add<0x4E>(v);   // quad_perm xor2
  v = dpp_add<0x141>(v);  // row_half_mirror (xor4)
  v = dpp_add<0x140>(v);  // row_mirror (xor8)
  return v;
}

// ---- staged reduce-scatter ----
// Each stage does the plain broadcast add v+dpp(v) on ALL live values (DPP source
// is a plain register, same as gred16), THEN halves the live set with a cndmask
// whose selector is INVARIANT under every later stage's lane permutation, so even
// compiler select-distribution through the exchange is sound. Add tree and
// own+recv order are bitwise-identical to gred16 per value (commutativity only).
// a[16] partials for j=0..15 -> returns the full 16-lane sum for j == L.
__device__ __forceinline__ float sred16(float* a, bool L0, bool L1, bool L2, bool L3) {
#pragma unroll
  for (int i = 0; i < 16; ++i) a[i] = a[i] + dppf<0xB1>(a[i]);
  float b[8];
#pragma unroll
  for (int m = 0; m < 8; ++m) b[m] = L0 ? a[2 * m + 1] : a[2 * m];   // j = 2m + L0
#pragma unroll
  for (int m = 0; m < 8; ++m) b[m] = b[m] + dppf<0x4E>(b[m]);
  float c[4];
#pragma unroll
  for (int m = 0; m < 4; ++m) c[m] = L1 ? b[2 * m + 1] : b[2 * m];   // j = 4m + (L&3)
#pragma unroll
  for (int m = 0; m < 4; ++m) c[m] = c[m] + swzf<0x101F>(c[m]);
  float d[2];
#pragma unroll
  for (int m = 0; m < 2; ++m) d[m] = L2 ? c[2 * m + 1] : c[2 * m];   // j = 8m + (L&7)
#pragma unroll
  for (int m = 0; m < 2; ++m) d[m] = d[m] + swzf<0x201F>(d[m]);
  return L3 ? d[1] : d[0];                                           // j == L
}

// a[4] partials for j=16..19 -> full sum for j == 16+(L&3), replicated across
// the four 4-lane slots. Same safety argument; final two stages are broadcast.
__device__ __forceinline__ float sred4(float* a, bool L0, bool L1) {
#pragma unroll
  for (int i = 0; i < 4; ++i) a[i] = a[i] + dppf<0xB1>(a[i]);
  float b[2];
  b[0] = L0 ? a[1] : a[0];   // j = 16 + L0
  b[1] = L0 ? a[3] : a[2];   // j = 18 + L0
#pragma unroll
  for (int m = 0; m < 2; ++m) b[m] = b[m] + dppf<0x4E>(b[m]);
  float c = L1 ? b[1] : b[0];          // j = 16 + (L&3)
  c = c + swzf<0x101F>(c);             // xor4 partner holds same j
  c = c + swzf<0x201F>(c);             // xor8 partner holds same j
  return c;
}

// 32-bit byte-offset gather helpers: base is wave-uniform (SGPR pair), offset is a
// 32-bit VGPR -> compiler emits global_load saddr (1 VALU addr op vs 64-bit mul/add)
__device__ __forceinline__ const vf4* vptr(const float* base, unsigned boff) {
  return (const vf4*)((const char*)base + boff);
}
__device__ __forceinline__ float ldf(const float* base, unsigned boff) {
  return *(const float*)((const char*)base + boff);
}

__global__ __launch_bounds__(256, 2) void walk_kernel(
    const float* __restrict__ x, const int* __restrict__ adj, const int* __restrict__ cur,
    const float* __restrict__ agent_w, const float* __restrict__ agent_gamma,
    const float* __restrict__ agent_beta, const float* __restrict__ agent_mean,
    const float* __restrict__ agent_var, const float* __restrict__ mom_w,
    const float* __restrict__ mom_gamma, const float* __restrict__ mom_beta,
    const float* __restrict__ mom_mean, const float* __restrict__ mom_var,
    float* __restrict__ xt, float* __restrict__ pa,
    float* __restrict__ out, float* __restrict__ sbuf,
    unsigned int* __restrict__ pflag) {
  __shared__ float lds_out[WPB * WSTRIDE];  // walk-phase out buffer; aliased as tile below
  const int tid  = threadIdx.x;
  const int lane = tid & 63;
  const int wv   = tid >> 6;
  const int g    = lane >> 4;
  const int L    = lane & 15;
  const bool L0 = L & 1, L1 = L & 2, L2 = L & 4, L3 = L & 8;
  const int b     = (blockIdx.x & 7) + (((blockIdx.x >> 8) & 1) << 3);
  const int chunk = (blockIdx.x >> 3) & 31;
  const int w     = wv * 4 + g;
  const int n     = chunk * WPB + w;
  const int c0    = L << 2;
  // consumer word offsets for the momentum-coeff scramble (data-is-flag):
  // word[2m]=S0[m], word[2m+1]=S1[m]; A0=word[(4n&1023)+off], A1=+2  (off = n>=256)
  const int mbase = (n << 2) & 1023;
  const int moff  = (chunk >= 16) ? 1 : 0;   // == (n >= 256), block-uniform

  // ================= phase 1: transpose + pa (fused, sc1 -> MALL) =================
  {
    float (*tile)[65] = (float (*)[65])lds_out;  // 64*65*4 = 16.6 KB, aliased
    const vf4 awp = *(const vf4*)(agent_w + (L << 2));
#pragma unroll 1
    for (int i = 0; i < 4; ++i) {
      const int t0 = ((chunk << 2) + i) << 6;
#pragma unroll
      for (int k = 0; k < 4; ++k) {
        int fid = tid + k * 256;
        int cc = fid >> 4, qt = (fid & 15) << 2;
        float4 vv = *(const float4*)(x + ((size_t)b * CDIM + cc) * TOT + t0 + qt);
        tile[cc][qt + 0] = vv.x; tile[cc][qt + 1] = vv.y;
        tile[cc][qt + 2] = vv.z; tile[cc][qt + 3] = vv.w;
      }
      __syncthreads();
#pragma unroll
      for (int k = 0; k < 4; ++k) {
        int fid = tid + k * 256;
        int tt = fid >> 4, qc = (fid & 15) << 2;
        vf4 vv = {tile[qc + 0][tt], tile[qc + 1][tt], tile[qc + 2][tt], tile[qc + 3][tt]};
        float* dst = xt + ((size_t)b * TOT + t0 + tt) * CDIM + qc;
        asm volatile("global_store_dwordx4 %0, %1, off sc0 sc1" :: "v"(dst), "v"(vv) : "memory");
        // fused pa: 16 lanes of this row hold channels qc..qc+3 of node tt;
        // gred16 == round-0's ((sA+sB)+(sC+sD)) balanced tree, bitwise-identical
        float part = gred16(dot4(vv.x, vv.y, vv.z, vv.w, awp.x, awp.y, awp.z, awp.w));
        if ((tid & 15) == 0)
          __hip_atomic_store(pa + (size_t)b * TOT + t0 + tt, part,
                             __ATOMIC_RELAXED, __HIP_MEMORY_SCOPE_AGENT);
      }
      __syncthreads();
    }
    asm volatile("s_waitcnt vmcnt(0)" ::: "memory");  // all sc1 stores at MALL
    __builtin_amdgcn_s_barrier();
    if (tid == 0)
      __hip_atomic_store(pflag + ((size_t)b * BPB + chunk) * LINE, MAGIC,
                         __ATOMIC_RELAXED, __HIP_MEMORY_SCOPE_AGENT);
    if (tid < BPB) {  // wait for all 32 blocks of this batch
      const unsigned int* f = pflag + ((size_t)b * BPB + tid) * LINE;
      while (__hip_atomic_load(f, __ATOMIC_RELAXED, __HIP_MEMORY_SCOPE_AGENT) != MAGIC)
        __builtin_amdgcn_s_sleep(2);
    }
    __builtin_amdgcn_s_barrier();
    asm volatile("" ::: "memory");
  }

  // ================= phase 2: the walk (data-is-flag sync) =================
  const vf4 aw2  = *(const vf4*)(agent_w + 64 + c0);
  const vf4 mw0a = *(const vf4*)(mom_w + c0);
  const vf4 mw0b = *(const vf4*)(mom_w + 64 + c0);
  const vf4 mw1a = *(const vf4*)(mom_w + 128 + c0);
  const vf4 mw1b = *(const vf4*)(mom_w + 192 + c0);
  const float amean  = agent_mean[0];
  const float abeta  = agent_beta[0];
  const float ainv   = agent_gamma[0] / sqrtf(agent_var[0] + 1e-5f);
  const float m0mean = mom_mean[0], m1mean = mom_mean[1];
  const float m0inv  = mom_gamma[0] / sqrtf(mom_var[0] + 1e-5f);
  const float m1inv  = mom_gamma[1] / sqrtf(mom_var[1] + 1e-5f);
  const float m0beta = mom_beta[0], m1beta = mom_beta[1];

  const float* xb   = xt + (size_t)b * TOT * CDIM;
  const float* pab  = pa + (size_t)b * TOT;
  const int*   adjb = adj + (size_t)b * TOT * KNB;
  float*       lout = lds_out + w * WSTRIDE;

  int t = cur[b * CN + n];
  vf4 pf = *vptr(xb, ((unsigned)t << 8) + (unsigned)(c0 << 2));
  vf4 cf = pf;
  vf4 u  = (vf4){0.f, 0.f, 0.f, 0.f};
  float A0v = 0.f, A1v = 0.f;

  vf4   nv[KNB];
  int   tL1, tL2;                // node id for this lane's j (j=L and j=16+(L&3))
  float pvL1, pvL2;              // pa[idx]*ainv for this lane's j
  float sqL1 = 0.f, sqL2 = 0.f;  // ||nv_j - cf|| for this lane's j (prev shadow)
  {
    const int4* arow = (const int4*)((const char*)adjb + (unsigned)t * 80u);
    int4 q0 = arow[0], q1 = arow[1], q2 = arow[2], q3 = arow[3], q4 = arow[4];
    int tmp[KNB] = {q0.x, q0.y, q0.z, q0.w, q1.x, q1.y, q1.z, q1.w,
                    q2.x, q2.y, q2.z, q2.w, q3.x, q3.y, q3.z, q3.w,
                    q4.x, q4.y, q4.z, q4.w};
#pragma unroll
    for (int j = 0; j < KNB; ++j)
      nv[j] = *vptr(xb, ((unsigned)tmp[j] << 8) + (unsigned)(c0 << 2));
    // lane-indexed j assignment (tmp values are lane-uniform; pick reg #L)
    tL1 = tmp[0];
#pragma unroll
    for (int j = 1; j < 16; ++j) tL1 = (L == j) ? tmp[j] : tL1;
    tL2 = tmp[16];
#pragma unroll
    for (int q = 1; q < 4; ++q) tL2 = ((L & 3) == q) ? tmp[16 + q] : tL2;
    pvL1 = ldf(pab, (unsigned)tL1 << 2) * ainv;
    pvL2 = ldf(pab, (unsigned)tL2 << 2) * ainv;
  }

  __builtin_amdgcn_s_setprio(1);   // walker chain is the global critical path
#pragma unroll 1
  for (int s = 0; s < NSTEPS; ++s) {
    float n1 = 0.f;
    if (s > 0) {
      // A0v/A1v came from the data-poll at the bottom of step s-1
      pf.x = A0v * cf.x + A1v * pf.x;
      pf.y = A0v * cf.y + A1v * pf.y;
      pf.z = A0v * cf.z + A1v * pf.z;
      pf.w = A0v * cf.w + A1v * pf.w;
      u.x = cf.x - pf.x; u.y = cf.y - pf.y; u.z = cf.z - pf.z; u.w = cf.w - pf.w;
      n1 = sqrtf(gred16(u.x * u.x + u.y * u.y + u.z * u.z + u.w * u.w));
    }
    float pw = gred16(pf.x * aw2.x + pf.y * aw2.y + pf.z * aw2.z + pf.w * aw2.w);
    // logit = pav[j]*ainv + lbase  ==  (pav[j]+pw-amean)*ainv + abeta  (~1e-7 reorder)
    float lbase = (pw - amean) * ainv + abeta;

    // per-lane candidate p for j=L (p1) and j=16+(L&3) (p2)
    float p1, p2;
    if (s > 0) {
      // su partials verbatim; sred trees bitwise == gred16 per j.
      float up[16], up2[4];
#pragma unroll
      for (int j = 0; j < 16; ++j) {
        const vf4 v = nv[j];
        float tx = v.x - cf.x, ty = v.y - cf.y, tz = v.z - cf.z, tw = v.w - cf.w;
        up[j] = tx * u.x + ty * u.y + tz * u.z + tw * u.w;
      }
#pragma unroll
      for (int q = 0; q < 4; ++q) {
        const vf4 v = nv[16 + q];
        float tx = v.x - cf.x, ty = v.y - cf.y, tz = v.z - cf.z, tw = v.w - cf.w;
        up2[q] = tx * u.x + ty * u.y + tz * u.z + tw * u.w;
      }
      float su1 = sred16(up, L0, L1, L2, L3);
      float su2 = sred4(up2, L0, L1);
      float den1  = fmaxf(n1 * sqL1, 1e-8f);
      float cos1  = su1 * __builtin_amdgcn_rcpf(den1);
      float dfac1 = fminf(fmaxf(1.0f + cos1, 0.0f), 1.0f);
      p1 = (pvL1 + lbase) * dfac1;
      float den2  = fmaxf(n1 * sqL2, 1e-8f);
      float cos2  = su2 * __builtin_amdgcn_rcpf(den2);
      float dfac2 = fminf(fmaxf(1.0f + cos2, 0.0f), 1.0f);
      p2 = (pvL2 + lbase) * dfac2;
    } else {
      p1 = pvL1 + lbase;
      p2 = pvL2 + lbase;
    }

    // argmax with first-max (lowest-j) semantics: local merge (j1 < j2 always,
    // so batch-2 wins only strictly), then 4-stage butterfly with j tie-break.
    // All lane-exchange sources below are plain registers (no select feeds a DPP).
    float bp; int bj, bt;
    {
      bool tk = p2 > p1;
      bp = tk ? p2 : p1;
      bj = tk ? (16 + (L & 3)) : L;
      bt = tk ? tL2 : tL1;
    }
#define AMAX_STAGE(GF, GI)                                        \
    {                                                             \
      float po = GF(bp); int jo = GI(bj); int to = GI(bt);        \
      bool better = (po > bp) || ((po == bp) && (jo < bj));       \
      bp = better ? po : bp;                                      \
      bj = better ? jo : bj;                                      \
      bt = better ? to : bt;                                      \
    }
    AMAX_STAGE(dppf<0xB1>, dppi<0xB1>)
    AMAX_STAGE(dppf<0x4E>, dppi<0x4E>)
    AMAX_STAGE(swzf<0x101F>, swzi<0x101F>)
    AMAX_STAGE(swzf<0x201F>, swzi<0x201F>)
#undef AMAX_STAGE

    // bestv: broadcast j* select over the register-resident neighborhood
    {
      vf4 bv = nv[0];
#pragma unroll
      for (int j = 1; j < KNB; ++j) {
        bool e = (bj == j);
        bv.x = e ? nv[j].x : bv.x;
        bv.y = e ? nv[j].y : bv.y;
        bv.z = e ? nv[j].z : bv.z;
        bv.w = e ? nv[j].w : bv.w;
      }
      cf = bv;
    }
    t = bt;
    lout[(c0 + 0) * 9 + s] = cf.x;
    lout[(c0 + 1) * 9 + s] = cf.y;
    lout[(c0 + 2) * 9 + s] = cf.z;
    lout[(c0 + 3) * 9 + s] = cf.w;

    if (s < NSTEPS - 1) {
      // ---- momentum logits for step s+1 (exact fused dot, unchanged); publish
      //      (S0,S1) as ONE packed 8-B relaxed store. Data IS the flag. ----
      float p0 = cf.x * mw0a.x + cf.y * mw0a.y + cf.z * mw0a.z + cf.w * mw0a.w +
                 pf.x * mw0b.x + pf.y * mw0b.y + pf.z * mw0b.z + pf.w * mw0b.w;
      float p1m = cf.x * mw1a.x + cf.y * mw1a.y + cf.z * mw1a.z + cf.w * mw1a.w +
                  pf.x * mw1b.x + pf.y * mw1b.y + pf.z * mw1b.z + pf.w * mw1b.w;
      p0  = gred16(p0);
      p1m = gred16(p1m);
      float mlog0 = (p0 - m0mean) * m0inv + m0beta;
      float mlog1 = (p1m - m1mean) * m1inv + m1beta;
      float mx = fmaxf(mlog0, mlog1);
      float e0 = expf(mlog0 - mx), e1 = expf(mlog1 - mx);
      float sinv = 1.0f / (e0 + e1);
      float* sb = sbuf + ((size_t)(b * NSTEPS + s + 1) << 10);
      if (L == 0) {
        unsigned long long pk =
            (unsigned long long)__float_as_uint(e0 * sinv) |
            ((unsigned long long)__float_as_uint(e1 * sinv) << 32);
        __hip_atomic_store((unsigned long long*)sb + n, pk,
                           __ATOMIC_RELAXED, __HIP_MEMORY_SCOPE_AGENT);
      }
      __builtin_amdgcn_s_setprio(0);   // shadow work below is hideable
      // ---- early poll issue: COMPILER-VISIBLE loads (no asm-output hazard);
      //      compiler schedules the loads here and waits before first use ----
      const unsigned* q0p = (const unsigned*)sb + mbase + moff;
      const unsigned* q2p = q0p + 2;
      unsigned w0 = __hip_atomic_load(q0p, __ATOMIC_RELAXED, __HIP_MEMORY_SCOPE_AGENT);
      unsigned w2 = __hip_atomic_load(q2p, __ATOMIC_RELAXED, __HIP_MEMORY_SCOPE_AGENT);
      // ---- prefetch next neighborhood (t-dependent only) ----
      const int4* arow = (const int4*)((const char*)adjb + (unsigned)t * 80u);
      int4 q0 = arow[0], q1 = arow[1], q2 = arow[2], q3 = arow[3], q4 = arow[4];
      int tmp[KNB] = {q0.x, q0.y, q0.z, q0.w, q1.x, q1.y, q1.z, q1.w,
                      q2.x, q2.y, q2.z, q2.w, q3.x, q3.y, q3.z, q3.w,
                      q4.x, q4.y, q4.z, q4.w};
#pragma unroll
      for (int j = 0; j < KNB; ++j)
        nv[j] = *vptr(xb, ((unsigned)tmp[j] << 8) + (unsigned)(c0 << 2));
      tL1 = tmp[0];
#pragma unroll
      for (int j = 1; j < 16; ++j) tL1 = (L == j) ? tmp[j] : tL1;
      tL2 = tmp[16];
#pragma unroll
      for (int q = 1; q < 4; ++q) tL2 = ((L & 3) == q) ? tmp[16 + q] : tL2;
      pvL1 = ldf(pab, (unsigned)tL1 << 2) * ainv;
      pvL2 = ldf(pab, (unsigned)tL2 << 2) * ainv;
      // ---- sq in the poll shadow: partials verbatim; sqrt AFTER the (bitwise-
      //      identical) reduce, on the same bits the old kernel sqrt'd ----
      {
        float sp[16], sp2[4];
#pragma unroll
        for (int j = 0; j < 16; ++j) {
          const vf4 v = nv[j];
          float tx = v.x - cf.x, ty = v.y - cf.y, tz = v.z - cf.z, tw = v.w - cf.w;
          sp[j] = tx * tx + ty * ty + tz * tz + tw * tw;
        }
#pragma unroll
        for (int q2i = 0; q2i < 4; ++q2i) {
          const vf4 v = nv[16 + q2i];
          float tx = v.x - cf.x, ty = v.y - cf.y, tz = v.z - cf.z, tw = v.w - cf.w;
          sp2[q2i] = tx * tx + ty * ty + tz * tz + tw * tw;
        }
        sqL1 = sqrtf(sred16(sp, L0, L1, L2, L3));
        sqL2 = sqrtf(sred4(sp2, L0, L1));
      }
      // ---- consume early loads; poll loop only if producers were late ----
      while (w0 == POISON || w2 == POISON) {
        __builtin_amdgcn_s_sleep(1);
        w0 = __hip_atomic_load(q0p, __ATOMIC_RELAXED, __HIP_MEMORY_SCOPE_AGENT);
        w2 = __hip_atomic_load(q2p, __ATOMIC_RELAXED, __HIP_MEMORY_SCOPE_AGENT);
      }
      A0v = __uint_as_float(w0);
      A1v = __uint_as_float(w2);
      __builtin_amdgcn_s_setprio(1);   // back on the critical chain
      asm volatile("" ::: "memory");
    }
  }

  // single coalesced write phase: out[b][c][n][0..7] = 32B per (c,n)
#pragma unroll
  for (int e = 0; e < 4; ++e) {
    const float* src = lout + (c0 + e) * 9;
    float4 w0 = make_float4(src[0], src[1], src[2], src[3]);
    float4 w1 = make_float4(src[4], src[5], src[6], src[7]);
    float* op = out + (((size_t)(b * CDIM + c0 + e) * CN) + n) * NSTEPS;
    *(float4*)(op)     = w0;
    *(float4*)(op + 4) = w1;
  }
}

extern "C" void kernel_launch(void* const* d_in, const int* in_sizes, int n_in,
                              void* d_out, int out_size, void* d_ws, size_t ws_size,
                              hipStream_t stream) {
  (void)in_sizes; (void)n_in; (void)out_size; (void)ws_size;
  const float* x          = (const float*)d_in[1];
  const int*   adj        = (const int*)d_in[2];
  const int*   cur        = (const int*)d_in[3];
  const float* agent_w    = (const float*)d_in[4];
  const float* agent_gamma= (const float*)d_in[5];
  const float* agent_beta = (const float*)d_in[6];
  const float* agent_mean = (const float*)d_in[7];
  const float* agent_var  = (const float*)d_in[8];
  const float* mom_w      = (const float*)d_in[9];
  const float* mom_gamma  = (const float*)d_in[10];
  const float* mom_beta   = (const float*)d_in[11];
  const float* mom_mean   = (const float*)d_in[12];
  const float* mom_var    = (const float*)d_in[13];
  float* out = (float*)d_out;

  char* ws = (char*)d_ws;
  const size_t xt_bytes   = (size_t)BN * TOT * CDIM * sizeof(float);       // 33.5 MB
  const size_t sbuf_bytes = (size_t)BN * NSTEPS * 2 * CN * sizeof(float);  // 512 KB
  const size_t pa_bytes   = (size_t)BN * TOT * sizeof(float);              // 512 KB
  float*        xt    = (float*)ws;
  float*        sbuf  = (float*)(ws + xt_bytes);   // per-step S pairs; poison = sentinel
  float*        pab   = (float*)(ws + xt_bytes + sbuf_bytes);
  unsigned int* pflag = (unsigned int*)(ws + xt_bytes + sbuf_bytes + pa_bytes);

  walk_kernel<<<BN * BPB, 256, 0, stream>>>(x, adj, cur, agent_w, agent_gamma, agent_beta,
                                            agent_mean, agent_var, mom_w, mom_gamma, mom_beta,
                                            mom_mean, mom_var, xt, pab, out, sbuf, pflag);
}